// Round 5
// baseline (128.814 us; speedup 1.0000x reference)
//
#include <hip/hip_runtime.h>
#include <math.h>

namespace {
constexpr int kH = 512;
constexpr int kN = 64;
constexpr int kL = 4096;
constexpr int kM = 2048;    // L/2
constexpr int kRec = 20;    // floats per (h,n) coefficient record
constexpr int kThreads = 256;
constexpr int kFftThreads = 512;
constexpr float kPi = 3.14159265358979323846f;
}

__device__ __forceinline__ int lpad(int i) { return i + (i >> 4); }

// ===================== Kernel 0: prep =====================
// One 64-thread block per head. Computes per-(h,n) SGPR-friendly coefficient
// records into d_ws, plus the (real) Nyquist bin value per head.
// Record: [ai, ar2, {a0,a1,b0,b1} x {00,01,10,11}, pad, pad]
//   s_r(l) += (a0 + a1*s) / D          s = 4t^2, t = tan(pi*l/L)
//   s_i(l) += t*(b0 + b1*s) / D        D = m1*m2 (product form; polynomial
//                                      form cancels at resonances: ar^2 can
//                                      be ~1e-7 while ai^4 ~1e5)
//   a0 = -2*C1*(vr*ar + vi*ai)   a1 = 2*(vi*ai - vr*ar)
//   b0 = -4*vr*(ar^2-ai^2) - 8*vi*ar*ai   b1 = -4*vr      [C1 = ar^2+ai^2]
__global__ __launch_bounds__(64)
void s4_prep(const float* __restrict__ A_real, const float* __restrict__ A_imag,
             const float* __restrict__ Bv, const float* __restrict__ Cv,
             const float* __restrict__ Pv, const float* __restrict__ inv_dt,
             float* __restrict__ cst, float* __restrict__ xnyq)
{
    const int h = blockIdx.x;
    const int n = threadIdx.x;
    const int idx = h * kN + n;
    const float dt = expf(inv_dt[h]);
    const float ar = -expf(A_real[idx]) * dt;   // Re(A*dt) (negative)
    const float ai =  A_imag[idx] * dt;         // Im(A*dt)
    const float br = Bv[idx*2+0], bi = Bv[idx*2+1];
    const float cr = Cv[idx*2+0], ci = Cv[idx*2+1];
    const float pr = Pv[idx*2+0], pi = Pv[idx*2+1];
    const float v00r = (br*cr - bi*ci)*dt, v00i = (br*ci + bi*cr)*dt;  // B*C
    const float v01r = (br*pr + bi*pi)*dt, v01i = (bi*pr - br*pi)*dt;  // B*conj(P)
    const float v10r = (pr*cr - pi*ci)*dt, v10i = (pr*ci + pi*cr)*dt;  // P*C
    const float v11r = (pr*pr + pi*pi)*dt;                              // |P|^2 (real)
    const float ar2 = ar*ar;
    const float C1  = ar2 + ai*ai;
    const float dd  = ar2 - ai*ai;

    float* r = cst + idx * kRec;
    r[0]  = ai;  r[1] = ar2;
    r[2]  = -2.f*C1*(v00r*ar + v00i*ai);  r[3]  = 2.f*(v00i*ai - v00r*ar);
    r[4]  = -4.f*v00r*dd - 8.f*v00i*ar*ai; r[5]  = -4.f*v00r;
    r[6]  = -2.f*C1*(v01r*ar + v01i*ai);  r[7]  = 2.f*(v01i*ai - v01r*ar);
    r[8]  = -4.f*v01r*dd - 8.f*v01i*ar*ai; r[9]  = -4.f*v01r;
    r[10] = -2.f*C1*(v10r*ar + v10i*ai);  r[11] = 2.f*(v10i*ai - v10r*ar);
    r[12] = -4.f*v10r*dd - 8.f*v10i*ar*ai; r[13] = -4.f*v10r;
    r[14] = -2.f*C1*(v11r*ar);            r[15] = -2.f*v11r*ar;
    r[16] = -4.f*v11r*dd;                 r[17] = -4.f*v11r;
    r[18] = 0.f; r[19] = 0.f;

    // Nyquist (u=0): k_f[2048] = sum_n Re(B*C)*dt  (real)
    float s = v00r;
    #pragma unroll
    for (int off = 32; off > 0; off >>= 1) s += __shfl_down(s, off, 64);
    if (n == 0) xnyq[h] = s;
}

// ===================== Kernel 1: spectrum =====================
// grid = 512 heads x 2 halves, 256 threads, 4 bins/thread.
// Per-n constants via wave-uniform s_load (SGPRs); each accumulation FMA has
// exactly one SGPR operand. 4 independent bin-chains hide the rcp/fma latency
// and amortize one record fetch over 100 lane-slots of work. No LDS.
__global__ __launch_bounds__(kThreads)
void s4_spectrum(const float* __restrict__ cst, float2* __restrict__ Xg)
{
    const int h    = blockIdx.x >> 1;
    const int half = blockIdx.x & 1;
    const int tid  = threadIdx.x;
    const int lbase = half * 1024 + tid;

    float tv[4], t2v[4], sv[4];
    #pragma unroll
    for (int b = 0; b < 4; ++b) {
        const int l = lbase + 256 * b;
        float sn, cn;
        sincosf((float)l * (kPi / (float)kL), &sn, &cn);
        tv[b]  = sn / cn;            // tan(pi*l/L), finite for l <= 2047
        t2v[b] = 2.f * tv[b];
        sv[b]  = t2v[b] * t2v[b];    // s = 4t^2
    }

    float s00r[4] = {0,0,0,0}, s00i[4] = {0,0,0,0};
    float s01r[4] = {0,0,0,0}, s01i[4] = {0,0,0,0};
    float s10r[4] = {0,0,0,0}, s10i[4] = {0,0,0,0};
    float s11r[4] = {0,0,0,0}, s11i[4] = {0,0,0,0};

    const float* rec = cst + (size_t)h * kN * kRec;
    #pragma unroll 2
    for (int n = 0; n < kN; ++n) {
        const float* r = rec + n * kRec;   // wave-uniform -> s_load
        const float ai = r[0], ar2 = r[1];
        const float c00a = r[2],  c00b = r[3],  c00c = r[4],  c00d = r[5];
        const float c01a = r[6],  c01b = r[7],  c01c = r[8],  c01d = r[9];
        const float c10a = r[10], c10b = r[11], c10c = r[12], c10d = r[13];
        const float c11a = r[14], c11b = r[15], c11c = r[16], c11d = r[17];
        #pragma unroll
        for (int b = 0; b < 4; ++b) {
            const float w1 = t2v[b] - ai, w2 = t2v[b] + ai;
            const float m1 = fmaf(w1, w1, ar2), m2 = fmaf(w2, w2, ar2);
            const float invD = __builtin_amdgcn_rcpf(m1 * m2);
            const float sD = sv[b] * invD, tD = tv[b] * invD, stD = sv[b] * tD;
            s00r[b] = fmaf(c00a, invD, s00r[b]); s00r[b] = fmaf(c00b, sD,  s00r[b]);
            s00i[b] = fmaf(c00c, tD,   s00i[b]); s00i[b] = fmaf(c00d, stD, s00i[b]);
            s01r[b] = fmaf(c01a, invD, s01r[b]); s01r[b] = fmaf(c01b, sD,  s01r[b]);
            s01i[b] = fmaf(c01c, tD,   s01i[b]); s01i[b] = fmaf(c01d, stD, s01i[b]);
            s10r[b] = fmaf(c10a, invD, s10r[b]); s10r[b] = fmaf(c10b, sD,  s10r[b]);
            s10i[b] = fmaf(c10c, tD,   s10i[b]); s10i[b] = fmaf(c10d, stD, s10i[b]);
            s11r[b] = fmaf(c11a, invD, s11r[b]); s11r[b] = fmaf(c11b, sD,  s11r[b]);
            s11i[b] = fmaf(c11c, tD,   s11i[b]); s11i[b] = fmaf(c11d, stD, s11i[b]);
        }
    }

    #pragma unroll
    for (int b = 0; b < 4; ++b) {
        const int l = lbase + 256 * b;
        const float nr = s01r[b]*s10r[b] - s01i[b]*s10i[b];
        const float ni = s01r[b]*s10i[b] + s01i[b]*s10r[b];
        const float dr = 1.f + s11r[b], di = s11i[b];
        const float qd = __builtin_amdgcn_rcpf(fmaf(dr, dr, di*di));
        const float wr = (nr*dr + ni*di) * qd;
        const float wi = (ni*dr - nr*di) * qd;
        const float gr = s00r[b] - wr, gi = s00i[b] - wi;
        // k_f = g * (1 + i*t)
        Xg[h*kM + l] = make_float2(fmaf(-gi, tv[b], gr), fmaf(gr, tv[b], gi));
    }
}

// ===================== Kernel 2: irfft =====================
// One 512-thread block per head. Packed-real 2048-pt inverse complex DFT in
// LDS with index padding i+(i>>4) to break power-of-2 bank aliasing.
__global__ __launch_bounds__(kFftThreads)
void s4_ifft(const float* __restrict__ xnyq, float* __restrict__ out)
{
    __shared__ float2 W2[kM + kM / 16];
    __shared__ float2 TW[kM / 2 + kM / 32];

    const int h   = blockIdx.x;
    const int tid = threadIdx.x;
    const float2* Xg = (const float2*)(out + (size_t)h * kL);
    const float nyqR = xnyq[h];

    for (int j = tid; j < kM / 2; j += kFftThreads) {
        float s, c;
        sincosf((2.0f * kPi / (float)kM) * (float)j, &s, &c);
        TW[lpad(j)] = make_float2(c, s);       // e^{+2pi i j / 2048}
    }

    // build Z (bit-reversed) from global X:
    // E = (X[k]+conj(X[M-k]))/2 ; O = e^{+2pi i k/L}*(X[k]-conj(X[M-k]))/2
    // Z[k] = (Er-Oi, Ei+Or); Z[M-k] = (Er+Oi, Or-Ei)
    for (int k = tid; k <= kM / 2; k += kFftThreads) {
        const float2 Xa = Xg[k];
        const float2 Xb = (k == 0) ? make_float2(nyqR, 0.0f) : Xg[kM - k];
        const float Er = 0.5f * (Xa.x + Xb.x);
        const float Ei = 0.5f * (Xa.y - Xb.y);
        const float Dr = 0.5f * (Xa.x - Xb.x);
        const float Di = 0.5f * (Xa.y + Xb.y);
        float s, c;
        sincosf((2.0f * kPi / (float)kL) * (float)k, &s, &c);
        const float Or = c * Dr - s * Di;
        const float Oi = c * Di + s * Dr;
        const int rk = (int)(__brev((unsigned)k) >> 21);          // 11-bit reversal
        W2[lpad(rk)] = make_float2(Er - Oi, Ei + Or);
        if (k != 0 && k != kM / 2) {
            const int rmk = (int)(__brev((unsigned)(kM - k)) >> 21);
            W2[lpad(rmk)] = make_float2(Er + Oi, Or - Ei);
        }
    }
    __syncthreads();

    for (int hs = 1; hs < kM; hs <<= 1) {
        const int tw_stride = (kM / 2) / hs;
        for (int j = tid; j < kM / 2; j += kFftThreads) {
            const int pos = j & (hs - 1);
            const int grp = j / hs;
            const int i0  = grp * 2 * hs + pos;
            const int i1  = i0 + hs;
            const float2 tw = TW[lpad(pos * tw_stride)];
            const float2 a = W2[lpad(i0)];
            const float2 b = W2[lpad(i1)];
            const float tr = tw.x * b.x - tw.y * b.y;
            const float ti = tw.x * b.y + tw.y * b.x;
            W2[lpad(i0)] = make_float2(a.x + tr, a.y + ti);
            W2[lpad(i1)] = make_float2(a.x - tr, a.y - ti);
        }
        __syncthreads();
    }

    const float invM = 1.0f / (float)kM;
    float2* out2 = (float2*)(out + (size_t)h * kL);
    for (int n = tid; n < kM; n += kFftThreads) {
        const float2 zn = W2[lpad(n)];
        out2[n] = make_float2(zn.x * invM, zn.y * invM);
    }
}

extern "C" void kernel_launch(void* const* d_in, const int* in_sizes, int n_in,
                              void* d_out, int out_size, void* d_ws, size_t ws_size,
                              hipStream_t stream) {
    const float* A_real = (const float*)d_in[0];
    const float* A_imag = (const float*)d_in[1];
    const float* B      = (const float*)d_in[2];
    const float* C      = (const float*)d_in[3];
    const float* P      = (const float*)d_in[4];
    const float* inv_dt = (const float*)d_in[5];
    float* out = (float*)d_out;

    float* cst  = (float*)d_ws;                       // 512*64*20 floats = 2.62 MB
    float* xnyq = cst + (size_t)kH * kN * kRec;       // +512 floats

    s4_prep<<<dim3(kH), dim3(64), 0, stream>>>(A_real, A_imag, B, C, P, inv_dt,
                                               cst, xnyq);
    s4_spectrum<<<dim3(kH * 2), dim3(kThreads), 0, stream>>>(cst, (float2*)out);
    s4_ifft<<<dim3(kH), dim3(kFftThreads), 0, stream>>>(xnyq, out);
}